// Round 16
// baseline (210.394 us; speedup 1.0000x reference)
//
#include <hip/hip_runtime.h>
#include <math.h>

#define BB 2
#define LL 4096
#define DD 1024
#define DS 16
#define RK 64
#define MM (BB*LL)        // 8192
#define NC 128            // scan chunks
#define LC (LL/NC)        // 32

typedef __attribute__((ext_vector_type(8))) short short8;
typedef __attribute__((ext_vector_type(4))) float f32x4;

__device__ __forceinline__ unsigned short f2bf(float f) {
    union { float f; unsigned u; } v; v.f = f;
    unsigned r = v.u + 0x7fff + ((v.u >> 16) & 1);
    return (unsigned short)(r >> 16);
}
__device__ __forceinline__ float bf2f(unsigned short u) {
    union { unsigned u; float f; } v; v.u = ((unsigned)u) << 16;
    return v.f;
}
__device__ __forceinline__ float2 bf2x2(unsigned u) {
    return make_float2(bf2f((unsigned short)u), bf2f((unsigned short)(u >> 16)));
}
__device__ __forceinline__ unsigned f2bfx2(float lo, float hi) {
    return (unsigned)f2bf(lo) | ((unsigned)f2bf(hi) << 16);
}
__device__ __forceinline__ float fast_rcp(float x) {
    return __builtin_amdgcn_rcpf(x);
}
__device__ __forceinline__ float silu_f(float v) {
    return v * fast_rcp(1.0f + __expf(-v));
}
__device__ __forceinline__ void gload16(const void* g, void* l) {
    __builtin_amdgcn_global_load_lds(
        (const __attribute__((address_space(1))) unsigned int*)g,
        (__attribute__((address_space(3))) unsigned int*)l, 16, 0, 0);
}

// ---------------- merged weight prep + LayerNorm (1 launch) ----------------
__global__ __launch_bounds__(256)
void prep_misc(const float* __restrict__ W_in, const float* __restrict__ W_out,
               const float* __restrict__ W_xp, const float* __restrict__ W_Bg,
               const float* __restrict__ W_Cg, const float* __restrict__ W_dt,
               const float* __restrict__ W_Bp, const float* __restrict__ W_Cp,
               unsigned short* __restrict__ WinT, unsigned short* __restrict__ WoutT,
               unsigned short* __restrict__ WgT, unsigned short* __restrict__ WdtT,
               float* __restrict__ WBpT, float* __restrict__ WCpT,
               const float* __restrict__ x, const float* __restrict__ gamma,
               const float* __restrict__ beta, unsigned short* __restrict__ xn_bf) {
    __shared__ float t[32][33];
    __shared__ float ss[4], qq[4];
    int b = blockIdx.x;
    if (b >= 4224) {
        int row = b - 4224;
        int tid = threadIdx.x;
        const float4* xr = (const float4*)(x + (size_t)row * DD);
        float4 v = xr[tid];
        float s = v.x + v.y + v.z + v.w;
        float q = v.x*v.x + v.y*v.y + v.z*v.z + v.w*v.w;
        #pragma unroll
        for (int off = 32; off > 0; off >>= 1) {
            s += __shfl_down(s, off);
            q += __shfl_down(q, off);
        }
        int wv = tid >> 6;
        if ((tid & 63) == 0) { ss[wv] = s; qq[wv] = q; }
        __syncthreads();
        float S = ss[0] + ss[1] + ss[2] + ss[3];
        float Q = qq[0] + qq[1] + qq[2] + qq[3];
        float mu  = S * (1.0f / DD);
        float var = Q * (1.0f / DD) - mu * mu;
        float r = rsqrtf(var + 1e-5f);
        int d0 = tid * 4;
        float4 gv = *(const float4*)(gamma + d0);
        float4 bv = *(const float4*)(beta + d0);
        ushort4 o;
        o.x = f2bf((v.x - mu) * r * gv.x + bv.x);
        o.y = f2bf((v.y - mu) * r * gv.y + bv.y);
        o.z = f2bf((v.z - mu) * r * gv.z + bv.z);
        o.w = f2bf((v.w - mu) * r * gv.w + bv.w);
        *(ushort4*)&xn_bf[(size_t)row * DD + d0] = o;
    } else if (b < 3072) {
        const float* W; unsigned short* WT; int K, N, n0, k0;
        if (b < 2048) { W = W_in;  WT = WinT;  K = DD; N = 2 * DD;
                        n0 = (b & 63) * 32; k0 = (b >> 6) * 32; }
        else { int bb = b - 2048; W = W_out; WT = WoutT; K = DD; N = DD;
               n0 = (bb & 31) * 32; k0 = (bb >> 5) * 32; }
        int tx = threadIdx.x & 31, ty = threadIdx.x >> 5;   // 32 x 8
        #pragma unroll
        for (int r = 0; r < 32; r += 8)
            t[ty + r][tx] = W[(size_t)(k0 + ty + r) * N + n0 + tx];
        __syncthreads();
        #pragma unroll
        for (int r = 0; r < 32; r += 8) {
            int nl = ty + r;
            WT[(size_t)(n0 + nl) * K + k0 + tx] = f2bf(t[tx][nl]);
        }
    } else if (b < 3584) {
        int idx = (b - 3072) * 256 + threadIdx.x;   // [n][k], k fastest
        int k = idx & 1023, n = idx >> 10;
        float v = 0.0f;
        if (n < 64)       v = W_xp[k * RK + n];
        else if (n < 80)  v = W_Bg[k * DS + (n - 64)];
        else if (n < 96)  v = W_Cg[k * DS + (n - 80)];
        WgT[idx] = f2bf(v);
    } else if (b < 4096) {
        int idx = (b - 3584) * 256 + threadIdx.x;   // [n][k], k fastest
        int k = idx & 127, n = idx >> 7;
        float v = (k < 64) ? W_dt[k * 1024 + n] : 0.0f;
        WdtT[idx] = f2bf(v);
    } else if (b < 4160) {
        int idx = (b - 4096) * 256 + threadIdx.x;   // d = idx>>4, k = idx&15
        WBpT[idx] = W_Bp[(idx & 15) * 1024 + (idx >> 4)];
    } else {
        int idx = (b - 4160) * 256 + threadIdx.x;
        WCpT[idx] = W_Cp[(idx & 15) * 1024 + (idx >> 4)];
    }
}

// ======== BMx256 8-wave pipelined MFMA GEMM (R5 schedule: 2 barriers/tile) ========
#define MF(a, b, c) __builtin_amdgcn_mfma_f32_16x16x32_bf16(a, b, c, 0, 0, 0)
template<int EPI, int BM>
__global__ __launch_bounds__(512, 1)
void gemm256(const unsigned short* __restrict__ A, const unsigned short* __restrict__ BT,
             void* __restrict__ C0v, void* __restrict__ C1v,
             const float* __restrict__ res, int M, int N, int K) {
    constexpr int MR = BM / 32;
    constexpr int RA = BM / 64;
    constexpr int ABUF = BM * 64;
    extern __shared__ unsigned short sm[];
    unsigned short* As = sm;
    unsigned short* Bs = sm + 2 * ABUF;
    const int tid = threadIdx.x;
    const int wave = tid >> 6, lane = tid & 63;
    const int wr = wave >> 2, wc = wave & 3;
    const int fr = lane & 15, fs = lane >> 4;

    int nbx = gridDim.x;
    int nwg = nbx * gridDim.y;
    int bid = blockIdx.y * nbx + blockIdx.x;
    int cpx = nwg >> 3;
    int swz = (bid & 7) * cpx + (bid >> 3);
    int by = swz / nbx, bx = swz - by * nbx;
    size_t rb = (size_t)by * BM, cb = (size_t)bx * 256;

    const int srow = tid >> 3;
    const int ssw  = (tid & 7) ^ (srow & 7);
    const unsigned short* gA = A + (rb + srow) * K + ssw * 8;
    const unsigned short* gB = BT + (cb + srow) * K + ssw * 8;
    const size_t rstep = (size_t)64 * K;
    unsigned short* dA = As + tid * 8;
    unsigned short* dB = Bs + tid * 8;
    const int T = K >> 6;

#define STGA(rnd, buf, kt) gload16(gA + (size_t)(rnd) * rstep + (size_t)(kt) * 64, dA + (buf) * ABUF + (rnd) * 4096)
#define STGB(rnd, buf, kt) gload16(gB + (size_t)(rnd) * rstep + (size_t)(kt) * 64, dB + (buf) * 16384 + (rnd) * 4096)
#define FOFF(r, S) (((r) << 6) + ((((S) ^ ((r) & 7))) << 3))
#define LDA(i, kk) (*(const short8*)&Ab[FOFF(arow0 + ((i) << 4), fs + ((kk) << 2))])
#define LDB(j, kk) (*(const short8*)&Bb[FOFF(brow0 + ((j) << 4), fs + ((kk) << 2))])

    const int arow0 = wr * (BM / 2) + fr;
    const int brow0 = wc * 64 + fr;

    f32x4 acc[MR][4] = {};

    #pragma unroll
    for (int r = 0; r < RA; ++r) STGA(r, 0, 0);
    #pragma unroll
    for (int r = 0; r < 4; ++r) STGB(r, 0, 0);

    #pragma unroll 1
    for (int t = 0; t < T; ++t) {
        const int cur = t & 1, nx = cur ^ 1;
        const bool pf = (t + 1) < T;
        const unsigned short* Ab = As + cur * ABUF;
        const unsigned short* Bb = Bs + cur * 16384;

        if (pf) { STGA(0, nx, t + 1); STGB(0, nx, t + 1); }
        if (pf) { asm volatile("s_waitcnt vmcnt(2)" ::: "memory"); }
        else    { asm volatile("s_waitcnt vmcnt(0)" ::: "memory"); }
        __builtin_amdgcn_s_barrier();
        __builtin_amdgcn_sched_barrier(0);

        short8 bfr[4][2];
        #pragma unroll
        for (int j = 0; j < 4; ++j) {
            bfr[j][0] = LDB(j, 0);
            bfr[j][1] = LDB(j, 1);
        }
        __builtin_amdgcn_s_setprio(1);
        #pragma unroll
        for (int ii = 0; ii < MR / 4; ++ii) {
            short8 a0 = LDA(ii, 0), a1 = LDA(ii, 1);
            #pragma unroll
            for (int j = 0; j < 4; ++j) {
                acc[ii][j] = MF(a0, bfr[j][0], acc[ii][j]);
                acc[ii][j] = MF(a1, bfr[j][1], acc[ii][j]);
            }
        }
        __builtin_amdgcn_s_setprio(0);
        __builtin_amdgcn_sched_barrier(0);

        #pragma unroll
        for (int p = 1; p < 4; ++p) {
            if (pf) {
                if (p < RA) STGA(p, nx, t + 1);
                STGB(p, nx, t + 1);
            }
            __builtin_amdgcn_s_setprio(1);
            #pragma unroll
            for (int ii = 0; ii < MR / 4; ++ii) {
                const int i = p * (MR / 4) + ii;
                short8 a0 = LDA(i, 0), a1 = LDA(i, 1);
                #pragma unroll
                for (int j = 0; j < 4; ++j) {
                    acc[i][j] = MF(a0, bfr[j][0], acc[i][j]);
                    acc[i][j] = MF(a1, bfr[j][1], acc[i][j]);
                }
            }
            __builtin_amdgcn_s_setprio(0);
            __builtin_amdgcn_sched_barrier(0);
        }
        __builtin_amdgcn_s_barrier();
    }

    const int row0 = (int)rb + wr * (BM / 2) + fs * 4;
    const int col0 = (int)cb + wc * 64 + fr;
    if (EPI == 1) {
        unsigned short* Cd = (cb < DD) ? (unsigned short*)C0v : (unsigned short*)C1v;
        const int cadj = (cb < DD) ? 0 : -DD;
        #pragma unroll
        for (int i = 0; i < MR; ++i)
            #pragma unroll
            for (int j = 0; j < 4; ++j) {
                int col = col0 + cadj + (j << 4);
                #pragma unroll
                for (int q = 0; q < 4; ++q)
                    Cd[(size_t)(row0 + (i << 4) + q) * DD + col] = f2bf(acc[i][j][q]);
            }
    } else {
        float* C0 = (float*)C0v;
        #pragma unroll
        for (int i = 0; i < MR; ++i)
            #pragma unroll
            for (int j = 0; j < 4; ++j) {
                int col = col0 + (j << 4);
                #pragma unroll
                for (int q = 0; q < 4; ++q) {
                    size_t off = (size_t)(row0 + (i << 4) + q) * N + col;
                    C0[off] = acc[i][j][q] + res[off];
                }
            }
    }
#undef STGA
#undef STGB
#undef FOFF
#undef LDA
#undef LDB
}

// ======== fused parameter chain: t = xact@WgT (K=1024); delta = softplus(t@WdtT + b) ========
// grid 64 blocks x 256 thr. t-tile (128x128) kept in LDS; B/C coeff cols 64..95 -> t_out.
__global__ __launch_bounds__(256)
void gemm_param(const unsigned short* __restrict__ xact, const unsigned short* __restrict__ WgT,
                const unsigned short* __restrict__ WdtT, const float* __restrict__ bias,
                unsigned short* __restrict__ t_out, unsigned short* __restrict__ delta) {
    extern __shared__ unsigned short sm[];
    unsigned short* As = sm;                 // 4096 ushorts (8 KB)
    unsigned short* Bs = sm + 4096;          // 8 KB
    unsigned short* tL = sm + 8192;          // 128*128 (32 KB)
    unsigned short* B2 = sm + 24576;         // 128*128 (32 KB)
    int tid = threadIdx.x;
    int rb = blockIdx.x * 128;
    int wave = tid >> 6, lane = tid & 63;
    int wr = wave >> 1, wc = wave & 1;
    int fr = lane & 15, fs = lane >> 4;

    // ---- stage 1: t = xact @ WgT, m97 single-buffer K-loop ----
    int r0 = tid >> 2, s0 = tid & 3;
    int sw0 = s0 ^ ((r0 >> 1) & 3);
    const unsigned short* gA = xact + (size_t)(rb + r0) * DD + sw0 * 8;
    const unsigned short* gB = WgT + (size_t)r0 * DD + sw0 * 8;
    size_t half = (size_t)64 * DD;
    char* lA0 = (char*)As + tid * 16;
    char* lA1 = (char*)As + (tid + 256) * 16;
    char* lB0 = (char*)Bs + tid * 16;
    char* lB1 = (char*)Bs + (tid + 256) * 16;

    f32x4 acc[4][4] = {};

    #pragma unroll 1
    for (int k0 = 0; k0 < DD; k0 += 32) {
        __syncthreads();
        gload16(gA + k0, lA0);
        gload16(gA + half + k0, lA1);
        gload16(gB + k0, lB0);
        gload16(gB + half + k0, lB1);
        __syncthreads();

        short8 af[4], bfr[4];
        #pragma unroll
        for (int i = 0; i < 4; i++) {
            int row = (wr << 6) + (i << 4) + fr;
            int off = (row << 5) + ((fs ^ ((row >> 1) & 3)) << 3);
            af[i] = *(const short8*)&As[off];
        }
        #pragma unroll
        for (int j = 0; j < 4; j++) {
            int row = (wc << 6) + (j << 4) + fr;
            int off = (row << 5) + ((fs ^ ((row >> 1) & 3)) << 3);
            bfr[j] = *(const short8*)&Bs[off];
        }
        #pragma unroll
        for (int i = 0; i < 4; i++)
            #pragma unroll
            for (int j = 0; j < 4; j++)
                acc[i][j] = MF(af[i], bfr[j], acc[i][j]);
    }

    // ---- write t-tile to LDS (seg^row&15 swizzle); B/C coeff cols -> HBM ----
    __syncthreads();
    {
        int row0l = (wr << 6) + (fs << 2);
        int col0l = (wc << 6) + fr;
        #pragma unroll
        for (int i = 0; i < 4; i++)
            #pragma unroll
            for (int j = 0; j < 4; j++) {
                int col = col0l + (j << 4);
                int seg = col >> 3, off = col & 7;
                #pragma unroll
                for (int q = 0; q < 4; q++) {
                    int row = row0l + (i << 4) + q;
                    unsigned short bv = f2bf(acc[i][j][q]);
                    tL[row * 128 + ((seg ^ (row & 15)) << 3) + off] = bv;
                    if (col >= 64 && col < 96)
                        t_out[(size_t)(rb + row) * 128 + col] = bv;
                }
            }
    }

    // ---- stage 2: delta = softplus(t @ WdtT + bias), 8 column-tiles ----
    int srow16 = tid >> 4, sseg = tid & 15;
    #pragma unroll 1
    for (int ct = 0; ct < 8; ++ct) {
        __syncthreads();                       // tL ready / prev B2 reads done
        #pragma unroll
        for (int r = 0; r < 8; ++r) {
            int row = r * 16 + srow16;
            int ss = sseg ^ (row & 15);
            gload16(WdtT + (size_t)(ct * 128 + row) * 128 + ss * 8,
                    (char*)B2 + r * 4096 + tid * 16);
        }
        asm volatile("s_waitcnt vmcnt(0)" ::: "memory");
        __syncthreads();

        f32x4 acc2[4][4] = {};
        #pragma unroll
        for (int kk = 0; kk < 4; ++kk) {
            short8 af[4], bfr[4];
            #pragma unroll
            for (int i = 0; i < 4; ++i) {
                int row = (wr << 6) + (i << 4) + fr;
                int s = (fs + (kk << 2)) ^ (row & 15);
                af[i] = *(const short8*)&tL[row * 128 + s * 8];
            }
            #pragma unroll
            for (int j = 0; j < 4; ++j) {
                int row = (wc << 6) + (j << 4) + fr;
                int s = (fs + (kk << 2)) ^ (row & 15);
                bfr[j] = *(const short8*)&B2[row * 128 + s * 8];
            }
            #pragma unroll
            for (int i = 0; i < 4; ++i)
                #pragma unroll
                for (int j = 0; j < 4; ++j)
                    acc2[i][j] = MF(af[i], bfr[j], acc2[i][j]);
        }

        int row0l = rb + (wr << 6) + (fs << 2);
        int col0l = ct * 128 + (wc << 6) + fr;
        #pragma unroll
        for (int i = 0; i < 4; ++i)
            #pragma unroll
            for (int j = 0; j < 4; ++j) {
                int col = col0l + (j << 4);
                float bv = bias[col];
                #pragma unroll
                for (int q = 0; q < 4; ++q) {
                    float v = acc2[i][j][q] + bv;
                    v = fmaxf(v, 0.0f) + __logf(1.0f + __expf(-fabsf(v)));
                    delta[(size_t)(row0l + (i << 4) + q) * DD + col] = f2bf(v);
                }
            }
    }
}

// ---------------- depthwise conv1d (K=3, SAME) + SiLU, bf16 in/out ----------------
__global__ __launch_bounds__(256)
void conv_silu(const unsigned short* __restrict__ xb, const float* __restrict__ cw,
               const float* __restrict__ cb, unsigned short* __restrict__ xact) {
    int bid = blockIdx.x;
    int cpx = gridDim.x >> 3;
    int swz = (bid & 7) * cpx + (bid >> 3);
    int idx8 = swz * 256 + threadIdx.x;
    size_t e = (size_t)idx8 * 8;
    int d0 = (int)(e & (DD - 1));
    int bl = (int)(e >> 10);
    int l = bl & (LL - 1);
    short8 cur = *(const short8*)&xb[e];
    short8 prv = {}, nxt = {};
    if (l > 0)      prv = *(const short8*)&xb[e - DD];
    if (l < LL - 1) nxt = *(const short8*)&xb[e + DD];
    short8 o;
    #pragma unroll
    for (int j = 0; j < 8; j++) {
        int d = d0 + j;
        float acc = cb[d];
        acc = fmaf(bf2f((unsigned short)prv[j]), cw[0 * DD + d], acc);
        acc = fmaf(bf2f((unsigned short)cur[j]), cw[1 * DD + d], acc);
        acc = fmaf(bf2f((unsigned short)nxt[j]), cw[2 * DD + d], acc);
        o[j] = (short)f2bf(silu_f(acc));
    }
    *(short8*)&xact[e] = o;
}

// ---------------- selective scan, chunked, 2-wide; B/C on the fly ----------------
__global__ __launch_bounds__(256)
void scan_p1(const unsigned short* __restrict__ delta, const unsigned short* __restrict__ xact,
             const unsigned short* __restrict__ t_bf, const float* __restrict__ WBpT,
             const float* __restrict__ A, float* __restrict__ P, float* __restrict__ Hc) {
    __shared__ float tbs[LC][16];
    int tid = threadIdx.x;
    int d = (blockIdx.x * 256 + tid) * 2;
    int c = blockIdx.y, b = blockIdx.z;
    int row0 = b * LL + c * LC;
    {
        int rr = tid >> 3, kp = (tid & 7) * 2;
        float2 f = bf2x2(*(const unsigned*)&t_bf[(size_t)(row0 + rr) * 128 + 64 + kp]);
        tbs[rr][kp] = f.x; tbs[rr][kp + 1] = f.y;
    }
    __syncthreads();
    float wB0[16], wB1[16];
    #pragma unroll
    for (int j = 0; j < 4; ++j) {
        *(float4*)&wB0[j * 4] = *(const float4*)&WBpT[(size_t)d * 16 + j * 4];
        *(float4*)&wB1[j * 4] = *(const float4*)&WBpT[(size_t)(d + 1) * 16 + j * 4];
    }
    float2 a_d = *(const float2*)&A[d];
    float h0 = 0.0f, h1 = 0.0f, sd0 = 0.0f, sd1 = 0.0f;
    #pragma unroll 4
    for (int i = 0; i < LC; i++) {
        size_t o = (size_t)(row0 + i) * DD + d;
        float2 dl = bf2x2(*(const unsigned*)&delta[o]);
        float2 xa = bf2x2(*(const unsigned*)&xact[o]);
        float bm0 = 0.0f, bm1 = 0.0f;
        #pragma unroll
        for (int j = 0; j < 4; ++j) {
            float4 t4 = *(const float4*)&tbs[i][j * 4];
            bm0 = fmaf(t4.x, wB0[j*4+0], bm0); bm1 = fmaf(t4.x, wB1[j*4+0], bm1);
            bm0 = fmaf(t4.y, wB0[j*4+1], bm0); bm1 = fmaf(t4.y, wB1[j*4+1], bm1);
            bm0 = fmaf(t4.z, wB0[j*4+2], bm0); bm1 = fmaf(t4.z, wB1[j*4+2], bm1);
            bm0 = fmaf(t4.w, wB0[j*4+3], bm0); bm1 = fmaf(t4.w, wB1[j*4+3], bm1);
        }
        float a0 = __expf(dl.x * a_d.x);
        float a1 = __expf(dl.y * a_d.y);
        h0 = fmaf(a0, h0, dl.x * bm0 * xa.x);
        h1 = fmaf(a1, h1, dl.y * bm1 * xa.y);
        sd0 += dl.x; sd1 += dl.y;
    }
    int pc = (b * NC + c) * DD + d;
    *(float2*)&P[pc]  = make_float2(__expf(a_d.x * sd0), __expf(a_d.y * sd1));
    *(float2*)&Hc[pc] = make_float2(h0, h1);
}

// ---- LDS-staged carry propagation: 16 blocks, 128 channels each ----
__global__ __launch_bounds__(256)
void scan_p2(const float* __restrict__ P, const float* __restrict__ Hc,
             float* __restrict__ hin) {
    extern __shared__ float sP[];            // [NC][128] P, then [NC][128] Hc
    float* sH = sP + NC * 128;
    int b = blockIdx.y;
    int d0 = blockIdx.x * 128;
    for (int idx = threadIdx.x; idx < NC * 128; idx += 256) {
        int c = idx >> 7, dd = idx & 127;
        int o = (b * NC + c) * DD + d0 + dd;
        sP[idx] = P[o];
        sH[idx] = Hc[o];
    }
    __syncthreads();
    if (threadIdx.x < 128) {
        int dd = threadIdx.x;
        float carry = 0.0f;
        #pragma unroll 4
        for (int c = 0; c < NC; ++c) {
            float pv = sP[c * 128 + dd];
            float hv = sH[c * 128 + dd];
            sP[c * 128 + dd] = carry;        // reuse as hin
            carry = fmaf(pv, carry, hv);
        }
    }
    __syncthreads();
    for (int idx = threadIdx.x; idx < NC * 128; idx += 256) {
        int c = idx >> 7, dd = idx & 127;
        hin[(b * NC + c) * DD + d0 + dd] = sP[idx];
    }
}

__global__ __launch_bounds__(256)
void scan_p3(const unsigned short* __restrict__ delta, const unsigned short* __restrict__ xact,
             const unsigned short* __restrict__ zb, const unsigned short* __restrict__ t_bf,
             const float* __restrict__ WBpT, const float* __restrict__ WCpT,
             const float* __restrict__ hin, const float* __restrict__ A,
             const float* __restrict__ Dsk, unsigned short* __restrict__ g) {
    __shared__ float tbs[LC][16];
    __shared__ float tcs[LC][16];
    int tid = threadIdx.x;
    int d = (blockIdx.x * 256 + tid) * 2;
    int c = blockIdx.y, b = blockIdx.z;
    int row0 = b * LL + c * LC;
    {
        int rr = tid >> 3, kp = (tid & 7) * 2;
        const unsigned short* tr = &t_bf[(size_t)(row0 + rr) * 128];
        float2 fb = bf2x2(*(const unsigned*)&tr[64 + kp]);
        float2 fc = bf2x2(*(const unsigned*)&tr[80 + kp]);
        tbs[rr][kp] = fb.x; tbs[rr][kp + 1] = fb.y;
        tcs[rr][kp] = fc.x; tcs[rr][kp + 1] = fc.y;
    }
    __syncthreads();
    float wB0[16], wB1[16], wC0[16], wC1[16];
    #pragma unroll
    for (int j = 0; j < 4; ++j) {
        *(float4*)&wB0[j * 4] = *(const float4*)&WBpT[(size_t)d * 16 + j * 4];
        *(float4*)&wB1[j * 4] = *(const float4*)&WBpT[(size_t)(d + 1) * 16 + j * 4];
        *(float4*)&wC0[j * 4] = *(const float4*)&WCpT[(size_t)d * 16 + j * 4];
        *(float4*)&wC1[j * 4] = *(const float4*)&WCpT[(size_t)(d + 1) * 16 + j * 4];
    }
    float2 a_d = *(const float2*)&A[d];
    float2 dsk = *(const float2*)&Dsk[d];
    float2 hv = *(const float2*)&hin[(b * NC + c) * DD + d];
    float h0 = hv.x, h1 = hv.y;
    #pragma unroll 4
    for (int i = 0; i < LC; i++) {
        size_t o = (size_t)(row0 + i) * DD + d;
        float2 dl = bf2x2(*(const unsigned*)&delta[o]);
        float2 xa = bf2x2(*(const unsigned*)&xact[o]);
        float2 zv = bf2x2(*(const unsigned*)&zb[o]);
        float bm0 = 0.0f, bm1 = 0.0f, cm0 = 0.0f, cm1 = 0.0f;
        #pragma unroll
        for (int j = 0; j < 4; ++j) {
            float4 t4 = *(const float4*)&tbs[i][j * 4];
            float4 c4 = *(const float4*)&tcs[i][j * 4];
            bm0 = fmaf(t4.x, wB0[j*4+0], bm0); bm1 = fmaf(t4.x, wB1[j*4+0], bm1);
            bm0 = fmaf(t4.y, wB0[j*4+1], bm0); bm1 = fmaf(t4.y, wB1[j*4+1], bm1);
            bm0 = fmaf(t4.z, wB0[j*4+2], bm0); bm1 = fmaf(t4.z, wB1[j*4+2], bm1);
            bm0 = fmaf(t4.w, wB0[j*4+3], bm0); bm1 = fmaf(t4.w, wB1[j*4+3], bm1);
            cm0 = fmaf(c4.x, wC0[j*4+0], cm0); cm1 = fmaf(c4.x, wC1[j*4+0], cm1);
            cm0 = fmaf(c4.y, wC0[j*4+1], cm0); cm1 = fmaf(c4.y, wC1[j*4+1], cm1);
            cm0 = fmaf(c4.z, wC0[j*4+2], cm0); cm1 = fmaf(c4.z, wC1[j*4+2], cm1);
            cm0 = fmaf(c4.w, wC0[j*4+3], cm0); cm1 = fmaf(c4.w, wC1[j*4+3], cm1);
        }
        float a0 = __expf(dl.x * a_d.x);
        float a1 = __expf(dl.y * a_d.y);
        h0 = fmaf(a0, h0, dl.x * bm0 * xa.x);
        h1 = fmaf(a1, h1, dl.y * bm1 * xa.y);
        float os0 = fmaf(xa.x, dsk.x, cm0 * h0);
        float os1 = fmaf(xa.y, dsk.y, cm1 * h1);
        float g0 = os0 * silu_f(zv.x);
        float g1 = os1 * silu_f(zv.y);
        *(unsigned*)&g[o] = f2bfx2(g0, g1);
    }
}

extern "C" void kernel_launch(void* const* d_in, const int* in_sizes, int n_in,
                              void* d_out, int out_size, void* d_ws, size_t ws_size,
                              hipStream_t stream) {
    const float* x      = (const float*)d_in[0];
    const float* gamma  = (const float*)d_in[1];
    const float* beta   = (const float*)d_in[2];
    const float* W_in   = (const float*)d_in[3];
    const float* conv_w = (const float*)d_in[4];
    const float* conv_b = (const float*)d_in[5];
    const float* W_xp   = (const float*)d_in[6];
    const float* W_Bg   = (const float*)d_in[7];
    const float* W_Cg   = (const float*)d_in[8];
    const float* W_dt   = (const float*)d_in[9];
    const float* b_dt   = (const float*)d_in[10];
    const float* W_Bp   = (const float*)d_in[11];
    const float* W_Cp   = (const float*)d_in[12];
    const float* A      = (const float*)d_in[13];
    const float* Dsk    = (const float*)d_in[14];
    const float* W_out  = (const float*)d_in[15];
    float* out = (float*)d_out;

    const size_t BIG = (size_t)MM * DD;
    char* p = (char*)d_ws;
    unsigned short* xn_bf   = (unsigned short*)p;  p += BIG * 2;       // reused as g
    unsigned short* xb_bf   = (unsigned short*)p;  p += BIG * 2;
    unsigned short* z_bf    = (unsigned short*)p;  p += BIG * 2;
    unsigned short* xact_bf = (unsigned short*)p;  p += BIG * 2;
    unsigned short* delta_bf= (unsigned short*)p;  p += BIG * 2;
    unsigned short* t_bf    = (unsigned short*)p;  p += (size_t)MM * 128 * 2;
    float* P     = (float*)p;                      p += (size_t)BB * NC * DD * 4;
    float* Hc    = (float*)p;                      p += (size_t)BB * NC * DD * 4;
    float* hin   = (float*)p;                      p += (size_t)BB * NC * DD * 4;
    unsigned short* WinT  = (unsigned short*)p;    p += (size_t)2 * DD * DD * 2;
    unsigned short* WoutT = (unsigned short*)p;    p += (size_t)DD * DD * 2;
    unsigned short* WgT   = (unsigned short*)p;    p += (size_t)128 * DD * 2;
    unsigned short* WdtT  = (unsigned short*)p;    p += (size_t)DD * 128 * 2;
    float* WBpT = (float*)p;                       p += (size_t)DD * 16 * 4;
    float* WCpT = (float*)p;                       p += (size_t)DD * 16 * 4;
    unsigned short* g_bf  = xn_bf;

    {
        void (*k1)(const unsigned short*, const unsigned short*, void*, void*,
                   const float*, int, int, int) = gemm256<1, 256>;
        void (*k2)(const unsigned short*, const unsigned short*, void*, void*,
                   const float*, int, int, int) = gemm256<2, 128>;
        void (*k3)(const float*, const float*, float*) = scan_p2;
        void (*k4)(const unsigned short*, const unsigned short*, const unsigned short*,
                   const float*, unsigned short*, unsigned short*) = gemm_param;
        (void)hipFuncSetAttribute((const void*)k1,
            hipFuncAttributeMaxDynamicSharedMemorySize, 131072);
        (void)hipFuncSetAttribute((const void*)k2,
            hipFuncAttributeMaxDynamicSharedMemorySize, 98304);
        (void)hipFuncSetAttribute((const void*)k3,
            hipFuncAttributeMaxDynamicSharedMemorySize, 131072);
        (void)hipFuncSetAttribute((const void*)k4,
            hipFuncAttributeMaxDynamicSharedMemorySize, 81920);
    }

    // 0. weight prep + LayerNorm (single launch)
    prep_misc<<<4224 + MM, 256, 0, stream>>>(W_in, W_out, W_xp, W_Bg, W_Cg,
                                             W_dt, W_Bp, W_Cp,
                                             WinT, WoutT, WgT, WdtT, WBpT, WCpT,
                                             x, gamma, beta, xn_bf);
    // 1. in_proj -> xb | z (bf16), 256x256 pipelined
    gemm256<1, 256><<<dim3(2 * DD / 256, MM / 256), 512, 131072, stream>>>(
        xn_bf, WinT, xb_bf, z_bf, nullptr, MM, 2 * DD, DD);
    // 2. depthwise conv + SiLU (XCD-chunked swizzle)
    conv_silu<<<(MM * DD / 8) / 256, 256, 0, stream>>>(xb_bf, conv_w, conv_b, xact_bf);
    // 3. fused param chain: t (LDS + B/C cols to HBM) -> delta (softplus)
    gemm_param<<<MM / 128, 256, 81920, stream>>>(xact_bf, WgT, WdtT, b_dt,
                                                 t_bf, delta_bf);
    // 4. chunked selective scan + gating; B/C on the fly, 2-wide, NC=128
    scan_p1<<<dim3(DD / 512, NC, BB), 256, 0, stream>>>(delta_bf, xact_bf, t_bf,
                                                        WBpT, A, P, Hc);
    scan_p2<<<dim3(DD / 128, BB), 256, 131072, stream>>>(P, Hc, hin);
    scan_p3<<<dim3(DD / 512, NC, BB), 256, 0, stream>>>(delta_bf, xact_bf, z_bf, t_bf,
                                                        WBpT, WCpT, hin, A, Dsk, g_bf);
    // 5. out_proj + residual (f32 out), 128x256 pipelined
    gemm256<2, 128><<<dim3(DD / 256, MM / 128), 512, 98304, stream>>>(
        g_bf, WoutT, out, nullptr, x, MM, DD, DD);
}

// Round 17
// 156.644 us; speedup vs baseline: 1.3431x; 1.3431x over previous
//
#include <hip/hip_runtime.h>
#include <math.h>

#define BB 2
#define LL 4096
#define DD 1024
#define DS 16
#define RK 64
#define MM (BB*LL)        // 8192
#define NC 128            // scan chunks
#define LC (LL/NC)        // 32

typedef __attribute__((ext_vector_type(8))) short short8;
typedef __attribute__((ext_vector_type(4))) float f32x4;

__device__ __forceinline__ unsigned short f2bf(float f) {
    union { float f; unsigned u; } v; v.f = f;
    unsigned r = v.u + 0x7fff + ((v.u >> 16) & 1);
    return (unsigned short)(r >> 16);
}
__device__ __forceinline__ float bf2f(unsigned short u) {
    union { unsigned u; float f; } v; v.u = ((unsigned)u) << 16;
    return v.f;
}
__device__ __forceinline__ float2 bf2x2(unsigned u) {
    return make_float2(bf2f((unsigned short)u), bf2f((unsigned short)(u >> 16)));
}
__device__ __forceinline__ unsigned f2bfx2(float lo, float hi) {
    return (unsigned)f2bf(lo) | ((unsigned)f2bf(hi) << 16);
}
__device__ __forceinline__ float fast_rcp(float x) {
    return __builtin_amdgcn_rcpf(x);
}
__device__ __forceinline__ float silu_f(float v) {
    return v * fast_rcp(1.0f + __expf(-v));
}
__device__ __forceinline__ void gload16(const void* g, void* l) {
    __builtin_amdgcn_global_load_lds(
        (const __attribute__((address_space(1))) unsigned int*)g,
        (__attribute__((address_space(3))) unsigned int*)l, 16, 0, 0);
}

// ---------------- merged weight prep + LayerNorm (1 launch) ----------------
__global__ __launch_bounds__(256)
void prep_misc(const float* __restrict__ W_in, const float* __restrict__ W_out,
               const float* __restrict__ W_xp, const float* __restrict__ W_Bg,
               const float* __restrict__ W_Cg, const float* __restrict__ W_dt,
               const float* __restrict__ W_Bp, const float* __restrict__ W_Cp,
               unsigned short* __restrict__ WinT, unsigned short* __restrict__ WoutT,
               unsigned short* __restrict__ WgT, unsigned short* __restrict__ WdtT,
               float* __restrict__ WBpT, float* __restrict__ WCpT,
               const float* __restrict__ x, const float* __restrict__ gamma,
               const float* __restrict__ beta, unsigned short* __restrict__ xn_bf) {
    __shared__ float t[32][33];
    __shared__ float ss[4], qq[4];
    int b = blockIdx.x;
    if (b >= 4224) {
        int row = b - 4224;
        int tid = threadIdx.x;
        const float4* xr = (const float4*)(x + (size_t)row * DD);
        float4 v = xr[tid];
        float s = v.x + v.y + v.z + v.w;
        float q = v.x*v.x + v.y*v.y + v.z*v.z + v.w*v.w;
        #pragma unroll
        for (int off = 32; off > 0; off >>= 1) {
            s += __shfl_down(s, off);
            q += __shfl_down(q, off);
        }
        int wv = tid >> 6;
        if ((tid & 63) == 0) { ss[wv] = s; qq[wv] = q; }
        __syncthreads();
        float S = ss[0] + ss[1] + ss[2] + ss[3];
        float Q = qq[0] + qq[1] + qq[2] + qq[3];
        float mu  = S * (1.0f / DD);
        float var = Q * (1.0f / DD) - mu * mu;
        float r = rsqrtf(var + 1e-5f);
        int d0 = tid * 4;
        float4 gv = *(const float4*)(gamma + d0);
        float4 bv = *(const float4*)(beta + d0);
        ushort4 o;
        o.x = f2bf((v.x - mu) * r * gv.x + bv.x);
        o.y = f2bf((v.y - mu) * r * gv.y + bv.y);
        o.z = f2bf((v.z - mu) * r * gv.z + bv.z);
        o.w = f2bf((v.w - mu) * r * gv.w + bv.w);
        *(ushort4*)&xn_bf[(size_t)row * DD + d0] = o;
    } else if (b < 3072) {
        const float* W; unsigned short* WT; int K, N, n0, k0;
        if (b < 2048) { W = W_in;  WT = WinT;  K = DD; N = 2 * DD;
                        n0 = (b & 63) * 32; k0 = (b >> 6) * 32; }
        else { int bb = b - 2048; W = W_out; WT = WoutT; K = DD; N = DD;
               n0 = (bb & 31) * 32; k0 = (bb >> 5) * 32; }
        int tx = threadIdx.x & 31, ty = threadIdx.x >> 5;   // 32 x 8
        #pragma unroll
        for (int r = 0; r < 32; r += 8)
            t[ty + r][tx] = W[(size_t)(k0 + ty + r) * N + n0 + tx];
        __syncthreads();
        #pragma unroll
        for (int r = 0; r < 32; r += 8) {
            int nl = ty + r;
            WT[(size_t)(n0 + nl) * K + k0 + tx] = f2bf(t[tx][nl]);
        }
    } else if (b < 3584) {
        int idx = (b - 3072) * 256 + threadIdx.x;   // [n][k], k fastest
        int k = idx & 1023, n = idx >> 10;
        float v = 0.0f;
        if (n < 64)       v = W_xp[k * RK + n];
        else if (n < 80)  v = W_Bg[k * DS + (n - 64)];
        else if (n < 96)  v = W_Cg[k * DS + (n - 80)];
        WgT[idx] = f2bf(v);
    } else if (b < 4096) {
        int idx = (b - 3584) * 256 + threadIdx.x;   // [n][k], k fastest
        int k = idx & 127, n = idx >> 7;
        float v = (k < 64) ? W_dt[k * 1024 + n] : 0.0f;
        WdtT[idx] = f2bf(v);
    } else if (b < 4160) {
        int idx = (b - 4096) * 256 + threadIdx.x;   // d = idx>>4, k = idx&15
        WBpT[idx] = W_Bp[(idx & 15) * 1024 + (idx >> 4)];
    } else {
        int idx = (b - 4160) * 256 + threadIdx.x;
        WCpT[idx] = W_Cp[(idx & 15) * 1024 + (idx >> 4)];
    }
}

// ======== BMx256 8-wave pipelined MFMA GEMM (R5 schedule: 2 barriers/tile) ========
#define MF(a, b, c) __builtin_amdgcn_mfma_f32_16x16x32_bf16(a, b, c, 0, 0, 0)
template<int EPI, int BM>
__global__ __launch_bounds__(512, 1)
void gemm256(const unsigned short* __restrict__ A, const unsigned short* __restrict__ BT,
             void* __restrict__ C0v, void* __restrict__ C1v,
             const float* __restrict__ res, int M, int N, int K) {
    constexpr int MR = BM / 32;
    constexpr int RA = BM / 64;
    constexpr int ABUF = BM * 64;
    extern __shared__ unsigned short sm[];
    unsigned short* As = sm;
    unsigned short* Bs = sm + 2 * ABUF;
    const int tid = threadIdx.x;
    const int wave = tid >> 6, lane = tid & 63;
    const int wr = wave >> 2, wc = wave & 3;
    const int fr = lane & 15, fs = lane >> 4;

    int nbx = gridDim.x;
    int nwg = nbx * gridDim.y;
    int bid = blockIdx.y * nbx + blockIdx.x;
    int cpx = nwg >> 3;
    int swz = (bid & 7) * cpx + (bid >> 3);
    int by = swz / nbx, bx = swz - by * nbx;
    size_t rb = (size_t)by * BM, cb = (size_t)bx * 256;

    const int srow = tid >> 3;
    const int ssw  = (tid & 7) ^ (srow & 7);
    const unsigned short* gA = A + (rb + srow) * K + ssw * 8;
    const unsigned short* gB = BT + (cb + srow) * K + ssw * 8;
    const size_t rstep = (size_t)64 * K;
    unsigned short* dA = As + tid * 8;
    unsigned short* dB = Bs + tid * 8;
    const int T = K >> 6;

#define STGA(rnd, buf, kt) gload16(gA + (size_t)(rnd) * rstep + (size_t)(kt) * 64, dA + (buf) * ABUF + (rnd) * 4096)
#define STGB(rnd, buf, kt) gload16(gB + (size_t)(rnd) * rstep + (size_t)(kt) * 64, dB + (buf) * 16384 + (rnd) * 4096)
#define FOFF(r, S) (((r) << 6) + ((((S) ^ ((r) & 7))) << 3))
#define LDA(i, kk) (*(const short8*)&Ab[FOFF(arow0 + ((i) << 4), fs + ((kk) << 2))])
#define LDB(j, kk) (*(const short8*)&Bb[FOFF(brow0 + ((j) << 4), fs + ((kk) << 2))])

    const int arow0 = wr * (BM / 2) + fr;
    const int brow0 = wc * 64 + fr;

    f32x4 acc[MR][4] = {};

    #pragma unroll
    for (int r = 0; r < RA; ++r) STGA(r, 0, 0);
    #pragma unroll
    for (int r = 0; r < 4; ++r) STGB(r, 0, 0);

    #pragma unroll 1
    for (int t = 0; t < T; ++t) {
        const int cur = t & 1, nx = cur ^ 1;
        const bool pf = (t + 1) < T;
        const unsigned short* Ab = As + cur * ABUF;
        const unsigned short* Bb = Bs + cur * 16384;

        if (pf) { STGA(0, nx, t + 1); STGB(0, nx, t + 1); }
        if (pf) { asm volatile("s_waitcnt vmcnt(2)" ::: "memory"); }
        else    { asm volatile("s_waitcnt vmcnt(0)" ::: "memory"); }
        __builtin_amdgcn_s_barrier();
        __builtin_amdgcn_sched_barrier(0);

        short8 bfr[4][2];
        #pragma unroll
        for (int j = 0; j < 4; ++j) {
            bfr[j][0] = LDB(j, 0);
            bfr[j][1] = LDB(j, 1);
        }
        __builtin_amdgcn_s_setprio(1);
        #pragma unroll
        for (int ii = 0; ii < MR / 4; ++ii) {
            short8 a0 = LDA(ii, 0), a1 = LDA(ii, 1);
            #pragma unroll
            for (int j = 0; j < 4; ++j) {
                acc[ii][j] = MF(a0, bfr[j][0], acc[ii][j]);
                acc[ii][j] = MF(a1, bfr[j][1], acc[ii][j]);
            }
        }
        __builtin_amdgcn_s_setprio(0);
        __builtin_amdgcn_sched_barrier(0);

        #pragma unroll
        for (int p = 1; p < 4; ++p) {
            if (pf) {
                if (p < RA) STGA(p, nx, t + 1);
                STGB(p, nx, t + 1);
            }
            __builtin_amdgcn_s_setprio(1);
            #pragma unroll
            for (int ii = 0; ii < MR / 4; ++ii) {
                const int i = p * (MR / 4) + ii;
                short8 a0 = LDA(i, 0), a1 = LDA(i, 1);
                #pragma unroll
                for (int j = 0; j < 4; ++j) {
                    acc[i][j] = MF(a0, bfr[j][0], acc[i][j]);
                    acc[i][j] = MF(a1, bfr[j][1], acc[i][j]);
                }
            }
            __builtin_amdgcn_s_setprio(0);
            __builtin_amdgcn_sched_barrier(0);
        }
        __builtin_amdgcn_s_barrier();
    }

    const int row0 = (int)rb + wr * (BM / 2) + fs * 4;
    const int col0 = (int)cb + wc * 64 + fr;
    if (EPI == 1) {
        unsigned short* Cd = (cb < DD) ? (unsigned short*)C0v : (unsigned short*)C1v;
        const int cadj = (cb < DD) ? 0 : -DD;
        #pragma unroll
        for (int i = 0; i < MR; ++i)
            #pragma unroll
            for (int j = 0; j < 4; ++j) {
                int col = col0 + cadj + (j << 4);
                #pragma unroll
                for (int q = 0; q < 4; ++q)
                    Cd[(size_t)(row0 + (i << 4) + q) * DD + col] = f2bf(acc[i][j][q]);
            }
    } else {
        float* C0 = (float*)C0v;
        #pragma unroll
        for (int i = 0; i < MR; ++i)
            #pragma unroll
            for (int j = 0; j < 4; ++j) {
                int col = col0 + (j << 4);
                #pragma unroll
                for (int q = 0; q < 4; ++q) {
                    size_t off = (size_t)(row0 + (i << 4) + q) * N + col;
                    C0[off] = acc[i][j][q] + res[off];
                }
            }
    }
#undef STGA
#undef STGB
#undef FOFF
#undef LDA
#undef LDB
}

// ---------------- single-shot K=128 delta up-proj GEMM + softplus ----------------
__global__ __launch_bounds__(256)
void gemm_up(const unsigned short* __restrict__ A, const unsigned short* __restrict__ BT,
             unsigned short* __restrict__ C, const float* __restrict__ bias, int N) {
    __shared__ unsigned short As[128 * 128];
    __shared__ unsigned short Bs[128 * 128];
    int tid = threadIdx.x;
    int rb = blockIdx.y * 128, cb = blockIdx.x * 128;
    int wave = tid >> 6, lane = tid & 63;
    int wr = wave >> 1, wc = wave & 1;
    int fr = lane & 15, fs = lane >> 4;

    int srow16 = tid >> 4, sseg = tid & 15;
    #pragma unroll
    for (int r = 0; r < 8; ++r) {
        int row = r * 16 + srow16;
        int ss = sseg ^ (row & 15);
        gload16(A + (size_t)(rb + row) * 128 + ss * 8, (char*)As + r * 4096 + tid * 16);
        gload16(BT + (size_t)(cb + row) * 128 + ss * 8, (char*)Bs + r * 4096 + tid * 16);
    }
    asm volatile("s_waitcnt vmcnt(0)" ::: "memory");
    __syncthreads();

    f32x4 acc[4][4] = {};
    #pragma unroll
    for (int kk = 0; kk < 4; ++kk) {
        short8 af[4], bfr[4];
        #pragma unroll
        for (int i = 0; i < 4; ++i) {
            int row = (wr << 6) + (i << 4) + fr;
            int s = (fs + (kk << 2)) ^ (row & 15);
            af[i] = *(const short8*)&As[row * 128 + s * 8];
        }
        #pragma unroll
        for (int j = 0; j < 4; ++j) {
            int row = (wc << 6) + (j << 4) + fr;
            int s = (fs + (kk << 2)) ^ (row & 15);
            bfr[j] = *(const short8*)&Bs[row * 128 + s * 8];
        }
        #pragma unroll
        for (int i = 0; i < 4; ++i)
            #pragma unroll
            for (int j = 0; j < 4; ++j)
                acc[i][j] = MF(af[i], bfr[j], acc[i][j]);
    }

    int row0 = rb + (wr << 6) + (fs << 2);
    int col0 = (wc << 6) + fr;
    #pragma unroll
    for (int i = 0; i < 4; ++i)
        #pragma unroll
        for (int j = 0; j < 4; ++j) {
            int col = cb + col0 + (j << 4);
            float bv = bias[col];
            #pragma unroll
            for (int q = 0; q < 4; ++q) {
                float v = acc[i][j][q] + bv;
                v = fmaxf(v, 0.0f) + __logf(1.0f + __expf(-fabsf(v)));
                C[(size_t)(row0 + (i << 4) + q) * N + col] = f2bf(v);
            }
        }
}

// ---------------- m97-style 128x128 MFMA GEMM: split-K partials (bf16) ----------------
__global__ __launch_bounds__(256)
void gemm_down(const unsigned short* __restrict__ A, const unsigned short* __restrict__ BT,
               unsigned short* __restrict__ C0, int M, int N, int K) {
    __shared__ unsigned short As[128 * 32];
    __shared__ unsigned short Bs[128 * 32];
    int tid = threadIdx.x;
    int rb = blockIdx.y * 128, cb = blockIdx.x * 128;
    int wave = tid >> 6, lane = tid & 63;
    int wr = wave >> 1, wc = wave & 1;
    int fr = lane & 15, fs = lane >> 4;

    int r0 = tid >> 2, s0 = tid & 3;
    int sw0 = s0 ^ ((r0 >> 1) & 3);
    const unsigned short* gA = A + (size_t)(rb + r0) * K + sw0 * 8;
    const unsigned short* gB = BT + (size_t)(cb + r0) * K + sw0 * 8;
    size_t half = (size_t)64 * K;
    char* lA0 = (char*)As + tid * 16;
    char* lA1 = (char*)As + (tid + 256) * 16;
    char* lB0 = (char*)Bs + tid * 16;
    char* lB1 = (char*)Bs + (tid + 256) * 16;

    int kb = blockIdx.z * (K >> 2), ke = kb + (K >> 2);

    f32x4 acc[4][4] = {};

    #pragma unroll 1
    for (int k0 = kb; k0 < ke; k0 += 32) {
        __syncthreads();
        gload16(gA + k0, lA0);
        gload16(gA + half + k0, lA1);
        gload16(gB + k0, lB0);
        gload16(gB + half + k0, lB1);
        __syncthreads();

        short8 af[4], bfr[4];
        #pragma unroll
        for (int i = 0; i < 4; i++) {
            int row = (wr << 6) + (i << 4) + fr;
            int off = (row << 5) + ((fs ^ ((row >> 1) & 3)) << 3);
            af[i] = *(const short8*)&As[off];
        }
        #pragma unroll
        for (int j = 0; j < 4; j++) {
            int row = (wc << 6) + (j << 4) + fr;
            int off = (row << 5) + ((fs ^ ((row >> 1) & 3)) << 3);
            bfr[j] = *(const short8*)&Bs[off];
        }
        #pragma unroll
        for (int i = 0; i < 4; i++)
            #pragma unroll
            for (int j = 0; j < 4; j++)
                acc[i][j] = MF(af[i], bfr[j], acc[i][j]);
    }

    int row0 = rb + (wr << 6) + (fs << 2);
    int col0 = (wc << 6) + fr;
    unsigned short* Cp = C0 + (size_t)blockIdx.z * M * N;
    #pragma unroll
    for (int i = 0; i < 4; i++)
        #pragma unroll
        for (int j = 0; j < 4; j++) {
            int col = cb + col0 + (j << 4);
            #pragma unroll
            for (int q = 0; q < 4; q++)
                Cp[(size_t)(row0 + (i << 4) + q) * N + col] = f2bf(acc[i][j][q]);
        }
}

// ---- reduce 4 split-K bf16 partials -> bf16 t ----
__global__ __launch_bounds__(256)
void reduce_t(const unsigned short* __restrict__ tp, unsigned short* __restrict__ t_bf) {
    int idx = blockIdx.x * 256 + threadIdx.x;
    const size_t Q = (size_t)MM * 128;
    ushort4 a = ((const ushort4*)tp)[idx];
    ushort4 b = ((const ushort4*)(tp + Q))[idx];
    ushort4 c = ((const ushort4*)(tp + 2 * Q))[idx];
    ushort4 d = ((const ushort4*)(tp + 3 * Q))[idx];
    ushort4 o;
    o.x = f2bf(bf2f(a.x) + bf2f(b.x) + bf2f(c.x) + bf2f(d.x));
    o.y = f2bf(bf2f(a.y) + bf2f(b.y) + bf2f(c.y) + bf2f(d.y));
    o.z = f2bf(bf2f(a.z) + bf2f(b.z) + bf2f(c.z) + bf2f(d.z));
    o.w = f2bf(bf2f(a.w) + bf2f(b.w) + bf2f(c.w) + bf2f(d.w));
    ((ushort4*)t_bf)[idx] = o;
}

// ---------------- depthwise conv1d (K=3, SAME) + SiLU, bf16 in/out ----------------
__global__ __launch_bounds__(256)
void conv_silu(const unsigned short* __restrict__ xb, const float* __restrict__ cw,
               const float* __restrict__ cb, unsigned short* __restrict__ xact) {
    int bid = blockIdx.x;
    int cpx = gridDim.x >> 3;
    int swz = (bid & 7) * cpx + (bid >> 3);
    int idx8 = swz * 256 + threadIdx.x;
    size_t e = (size_t)idx8 * 8;
    int d0 = (int)(e & (DD - 1));
    int bl = (int)(e >> 10);
    int l = bl & (LL - 1);
    short8 cur = *(const short8*)&xb[e];
    short8 prv = {}, nxt = {};
    if (l > 0)      prv = *(const short8*)&xb[e - DD];
    if (l < LL - 1) nxt = *(const short8*)&xb[e + DD];
    short8 o;
    #pragma unroll
    for (int j = 0; j < 8; j++) {
        int d = d0 + j;
        float acc = cb[d];
        acc = fmaf(bf2f((unsigned short)prv[j]), cw[0 * DD + d], acc);
        acc = fmaf(bf2f((unsigned short)cur[j]), cw[1 * DD + d], acc);
        acc = fmaf(bf2f((unsigned short)nxt[j]), cw[2 * DD + d], acc);
        o[j] = (short)f2bf(silu_f(acc));
    }
    *(short8*)&xact[e] = o;
}

// ---------------- selective scan, chunked, 2-wide; B/C on the fly ----------------
__global__ __launch_bounds__(256)
void scan_p1(const unsigned short* __restrict__ delta, const unsigned short* __restrict__ xact,
             const unsigned short* __restrict__ t_bf, const float* __restrict__ WBpT,
             const float* __restrict__ A, float* __restrict__ P, float* __restrict__ Hc) {
    __shared__ float tbs[LC][16];
    int tid = threadIdx.x;
    int d = (blockIdx.x * 256 + tid) * 2;
    int c = blockIdx.y, b = blockIdx.z;
    int row0 = b * LL + c * LC;
    {
        int rr = tid >> 3, kp = (tid & 7) * 2;
        float2 f = bf2x2(*(const unsigned*)&t_bf[(size_t)(row0 + rr) * 128 + 64 + kp]);
        tbs[rr][kp] = f.x; tbs[rr][kp + 1] = f.y;
    }
    __syncthreads();
    float wB0[16], wB1[16];
    #pragma unroll
    for (int j = 0; j < 4; ++j) {
        *(float4*)&wB0[j * 4] = *(const float4*)&WBpT[(size_t)d * 16 + j * 4];
        *(float4*)&wB1[j * 4] = *(const float4*)&WBpT[(size_t)(d + 1) * 16 + j * 4];
    }
    float2 a_d = *(const float2*)&A[d];
    float h0 = 0.0f, h1 = 0.0f, sd0 = 0.0f, sd1 = 0.0f;
    #pragma unroll 4
    for (int i = 0; i < LC; i++) {
        size_t o = (size_t)(row0 + i) * DD + d;
        float2 dl = bf2x2(*(const unsigned*)&delta[o]);
        float2 xa = bf2x2(*(const unsigned*)&xact[o]);
        float bm0 = 0.0f, bm1 = 0.0f;
        #pragma unroll
        for (int j = 0; j < 4; ++j) {
            float4 t4 = *(const float4*)&tbs[i][j * 4];
            bm0 = fmaf(t4.x, wB0[j*4+0], bm0); bm1 = fmaf(t4.x, wB1[j*4+0], bm1);
            bm0 = fmaf(t4.y, wB0[j*4+1], bm0); bm1 = fmaf(t4.y, wB1[j*4+1], bm1);
            bm0 = fmaf(t4.z, wB0[j*4+2], bm0); bm1 = fmaf(t4.z, wB1[j*4+2], bm1);
            bm0 = fmaf(t4.w, wB0[j*4+3], bm0); bm1 = fmaf(t4.w, wB1[j*4+3], bm1);
        }
        float a0 = __expf(dl.x * a_d.x);
        float a1 = __expf(dl.y * a_d.y);
        h0 = fmaf(a0, h0, dl.x * bm0 * xa.x);
        h1 = fmaf(a1, h1, dl.y * bm1 * xa.y);
        sd0 += dl.x; sd1 += dl.y;
    }
    int pc = (b * NC + c) * DD + d;
    *(float2*)&P[pc]  = make_float2(__expf(a_d.x * sd0), __expf(a_d.y * sd1));
    *(float2*)&Hc[pc] = make_float2(h0, h1);
}

// ---- LDS-staged carry propagation: 16 blocks, 128 channels each ----
__global__ __launch_bounds__(256)
void scan_p2(const float* __restrict__ P, const float* __restrict__ Hc,
             float* __restrict__ hin) {
    extern __shared__ float sP[];            // [NC][128] P, then [NC][128] Hc
    float* sH = sP + NC * 128;
    int b = blockIdx.y;
    int d0 = blockIdx.x * 128;
    for (int idx = threadIdx.x; idx < NC * 128; idx += 256) {
        int c = idx >> 7, dd = idx & 127;
        int o = (b * NC + c) * DD + d0 + dd;
        sP[idx] = P[o];
        sH[idx] = Hc[o];
    }
    __syncthreads();
    if (threadIdx.x < 128) {
        int dd = threadIdx.x;
        float carry = 0.0f;
        #pragma unroll 4
        for (int c = 0; c < NC; ++c) {
            float pv = sP[c * 128 + dd];
            float hv = sH[c * 128 + dd];
            sP[c * 128 + dd] = carry;        // reuse as hin
            carry = fmaf(pv, carry, hv);
        }
    }
    __syncthreads();
    for (int idx = threadIdx.x; idx < NC * 128; idx += 256) {
        int c = idx >> 7, dd = idx & 127;
        hin[(b * NC + c) * DD + d0 + dd] = sP[idx];
    }
}

__global__ __launch_bounds__(256)
void scan_p3(const unsigned short* __restrict__ delta, const unsigned short* __restrict__ xact,
             const unsigned short* __restrict__ zb, const unsigned short* __restrict__ t_bf,
             const float* __restrict__ WBpT, const float* __restrict__ WCpT,
             const float* __restrict__ hin, const float* __restrict__ A,
             const float* __restrict__ Dsk, unsigned short* __restrict__ g) {
    __shared__ float tbs[LC][16];
    __shared__ float tcs[LC][16];
    int tid = threadIdx.x;
    int d = (blockIdx.x * 256 + tid) * 2;
    int c = blockIdx.y, b = blockIdx.z;
    int row0 = b * LL + c * LC;
    {
        int rr = tid >> 3, kp = (tid & 7) * 2;
        const unsigned short* tr = &t_bf[(size_t)(row0 + rr) * 128];
        float2 fb = bf2x2(*(const unsigned*)&tr[64 + kp]);
        float2 fc = bf2x2(*(const unsigned*)&tr[80 + kp]);
        tbs[rr][kp] = fb.x; tbs[rr][kp + 1] = fb.y;
        tcs[rr][kp] = fc.x; tcs[rr][kp + 1] = fc.y;
    }
    __syncthreads();
    float wB0[16], wB1[16], wC0[16], wC1[16];
    #pragma unroll
    for (int j = 0; j < 4; ++j) {
        *(float4*)&wB0[j * 4] = *(const float4*)&WBpT[(size_t)d * 16 + j * 4];
        *(float4*)&wB1[j * 4] = *(const float4*)&WBpT[(size_t)(d + 1) * 16 + j * 4];
        *(float4*)&wC0[j * 4] = *(const float4*)&WCpT[(size_t)d * 16 + j * 4];
        *(float4*)&wC1[j * 4] = *(const float4*)&WCpT[(size_t)(d + 1) * 16 + j * 4];
    }
    float2 a_d = *(const float2*)&A[d];
    float2 dsk = *(const float2*)&Dsk[d];
    float2 hv = *(const float2*)&hin[(b * NC + c) * DD + d];
    float h0 = hv.x, h1 = hv.y;
    #pragma unroll 4
    for (int i = 0; i < LC; i++) {
        size_t o = (size_t)(row0 + i) * DD + d;
        float2 dl = bf2x2(*(const unsigned*)&delta[o]);
        float2 xa = bf2x2(*(const unsigned*)&xact[o]);
        float2 zv = bf2x2(*(const unsigned*)&zb[o]);
        float bm0 = 0.0f, bm1 = 0.0f, cm0 = 0.0f, cm1 = 0.0f;
        #pragma unroll
        for (int j = 0; j < 4; ++j) {
            float4 t4 = *(const float4*)&tbs[i][j * 4];
            float4 c4 = *(const float4*)&tcs[i][j * 4];
            bm0 = fmaf(t4.x, wB0[j*4+0], bm0); bm1 = fmaf(t4.x, wB1[j*4+0], bm1);
            bm0 = fmaf(t4.y, wB0[j*4+1], bm0); bm1 = fmaf(t4.y, wB1[j*4+1], bm1);
            bm0 = fmaf(t4.z, wB0[j*4+2], bm0); bm1 = fmaf(t4.z, wB1[j*4+2], bm1);
            bm0 = fmaf(t4.w, wB0[j*4+3], bm0); bm1 = fmaf(t4.w, wB1[j*4+3], bm1);
            cm0 = fmaf(c4.x, wC0[j*4+0], cm0); cm1 = fmaf(c4.x, wC1[j*4+0], cm1);
            cm0 = fmaf(c4.y, wC0[j*4+1], cm0); cm1 = fmaf(c4.y, wC1[j*4+1], cm1);
            cm0 = fmaf(c4.z, wC0[j*4+2], cm0); cm1 = fmaf(c4.z, wC1[j*4+2], cm1);
            cm0 = fmaf(c4.w, wC0[j*4+3], cm0); cm1 = fmaf(c4.w, wC1[j*4+3], cm1);
        }
        float a0 = __expf(dl.x * a_d.x);
        float a1 = __expf(dl.y * a_d.y);
        h0 = fmaf(a0, h0, dl.x * bm0 * xa.x);
        h1 = fmaf(a1, h1, dl.y * bm1 * xa.y);
        float os0 = fmaf(xa.x, dsk.x, cm0 * h0);
        float os1 = fmaf(xa.y, dsk.y, cm1 * h1);
        float g0 = os0 * silu_f(zv.x);
        float g1 = os1 * silu_f(zv.y);
        *(unsigned*)&g[o] = f2bfx2(g0, g1);
    }
}

extern "C" void kernel_launch(void* const* d_in, const int* in_sizes, int n_in,
                              void* d_out, int out_size, void* d_ws, size_t ws_size,
                              hipStream_t stream) {
    const float* x      = (const float*)d_in[0];
    const float* gamma  = (const float*)d_in[1];
    const float* beta   = (const float*)d_in[2];
    const float* W_in   = (const float*)d_in[3];
    const float* conv_w = (const float*)d_in[4];
    const float* conv_b = (const float*)d_in[5];
    const float* W_xp   = (const float*)d_in[6];
    const float* W_Bg   = (const float*)d_in[7];
    const float* W_Cg   = (const float*)d_in[8];
    const float* W_dt   = (const float*)d_in[9];
    const float* b_dt   = (const float*)d_in[10];
    const float* W_Bp   = (const float*)d_in[11];
    const float* W_Cp   = (const float*)d_in[12];
    const float* A      = (const float*)d_in[13];
    const float* Dsk    = (const float*)d_in[14];
    const float* W_out  = (const float*)d_in[15];
    float* out = (float*)d_out;

    const size_t BIG = (size_t)MM * DD;
    char* p = (char*)d_ws;
    unsigned short* xn_bf   = (unsigned short*)p;  p += BIG * 2;       // reused as g
    unsigned short* xb_bf   = (unsigned short*)p;  p += BIG * 2;
    unsigned short* z_bf    = (unsigned short*)p;  p += BIG * 2;
    unsigned short* xact_bf = (unsigned short*)p;  p += BIG * 2;
    unsigned short* delta_bf= (unsigned short*)p;  p += BIG * 2;
    unsigned short* t_bf    = (unsigned short*)p;  p += (size_t)MM * 128 * 2;
    unsigned short* tpart   = (unsigned short*)p;  p += (size_t)4 * MM * 128 * 2;
    float* P     = (float*)p;                      p += (size_t)BB * NC * DD * 4;
    float* Hc    = (float*)p;                      p += (size_t)BB * NC * DD * 4;
    float* hin   = (float*)p;                      p += (size_t)BB * NC * DD * 4;
    unsigned short* WinT  = (unsigned short*)p;    p += (size_t)2 * DD * DD * 2;
    unsigned short* WoutT = (unsigned short*)p;    p += (size_t)DD * DD * 2;
    unsigned short* WgT   = (unsigned short*)p;    p += (size_t)128 * DD * 2;
    unsigned short* WdtT  = (unsigned short*)p;    p += (size_t)DD * 128 * 2;
    float* WBpT = (float*)p;                       p += (size_t)DD * 16 * 4;
    float* WCpT = (float*)p;                       p += (size_t)DD * 16 * 4;
    unsigned short* g_bf  = xn_bf;

    {
        void (*k1)(const unsigned short*, const unsigned short*, void*, void*,
                   const float*, int, int, int) = gemm256<1, 256>;
        void (*k2)(const unsigned short*, const unsigned short*, void*, void*,
                   const float*, int, int, int) = gemm256<2, 128>;
        void (*k3)(const float*, const float*, float*) = scan_p2;
        (void)hipFuncSetAttribute((const void*)k1,
            hipFuncAttributeMaxDynamicSharedMemorySize, 131072);
        (void)hipFuncSetAttribute((const void*)k2,
            hipFuncAttributeMaxDynamicSharedMemorySize, 98304);
        (void)hipFuncSetAttribute((const void*)k3,
            hipFuncAttributeMaxDynamicSharedMemorySize, 131072);
    }

    // 0. weight prep + LayerNorm (single launch)
    prep_misc<<<4224 + MM, 256, 0, stream>>>(W_in, W_out, W_xp, W_Bg, W_Cg,
                                             W_dt, W_Bp, W_Cp,
                                             WinT, WoutT, WgT, WdtT, WBpT, WCpT,
                                             x, gamma, beta, xn_bf);
    // 1. in_proj -> xb | z (bf16), 256x256 pipelined
    gemm256<1, 256><<<dim3(2 * DD / 256, MM / 256), 512, 131072, stream>>>(
        xn_bf, WinT, xb_bf, z_bf, nullptr, MM, 2 * DD, DD);
    // 2. depthwise conv + SiLU (XCD-chunked swizzle)
    conv_silu<<<(MM * DD / 8) / 256, 256, 0, stream>>>(xb_bf, conv_w, conv_b, xact_bf);
    // 3a. down-proj (split-K=4, bf16 partials) + reduce -> t (M x 128 bf16)
    gemm_down<<<dim3(1, MM / 128, 4), 256, 0, stream>>>(
        xact_bf, WgT, tpart, MM, 128, DD);
    reduce_t<<<(MM * 128 / 4) / 256, 256, 0, stream>>>(tpart, t_bf);
    // 3b. delta up-proj (M x 1024) with softplus epilogue
    gemm_up<<<dim3(DD / 128, MM / 128), 256, 0, stream>>>(
        t_bf, WdtT, delta_bf, b_dt, DD);
    // 4. chunked selective scan + gating; B/C on the fly, 2-wide, NC=128
    scan_p1<<<dim3(DD / 512, NC, BB), 256, 0, stream>>>(delta_bf, xact_bf, t_bf,
                                                        WBpT, A, P, Hc);
    scan_p2<<<dim3(DD / 128, BB), 256, 131072, stream>>>(P, Hc, hin);
    scan_p3<<<dim3(DD / 512, NC, BB), 256, 0, stream>>>(delta_bf, xact_bf, z_bf, t_bf,
                                                        WBpT, WCpT, hin, A, Dsk, g_bf);
    // 5. out_proj + residual (f32 out), 128x256 pipelined
    gemm256<2, 128><<<dim3(DD / 256, MM / 128), 512, 98304, stream>>>(
        g_bf, WoutT, out, nullptr, x, MM, DD, DD);
}